// Round 19
// baseline (289.569 us; speedup 1.0000x reference)
//
#include <hip/hip_runtime.h>

// Problem: T=128, B=64, STATE=32, LATENT=16, AC=8, MS=8, SE=64, AE=16, H=64, OUT=18
// d_out layout: [0] = kl_loss, [1 .. 8192] = recon_loss[s*64+b]  (out_size = 8193, f32)
// d_ws layout:  [0, 4194304)        xh  (T*B, 256) f16: [0:64)=ir,[64:128)=iz,[128:192)=i_n,[192:256)=hid0
//               [4194304, 4227072)  aux (T*B) int: sign bit = done, low bits = action
//               [4227072, +32)      8 work-steal counters (one per XCD queue)

#define XH_OFF   0
#define AUX_OFF  4194304
#define CTR_OFF  4227072

typedef float f32x16 __attribute__((ext_vector_type(16)));
typedef _Float16 h2 __attribute__((ext_vector_type(2)));

// splat one half of a packed f16 pair across both halves (op_sel on pk ops)
__device__ __forceinline__ h2 sp0(h2 v) { return __builtin_shufflevector(v, v, 0, 0); }
__device__ __forceinline__ h2 sp1(h2 v) { return __builtin_shufflevector(v, v, 1, 1); }

// after this, lane15 holds sum(lanes 0..15), lane31 holds sum(lanes 16..31) (row_shr scan)
__device__ __forceinline__ float row16_scan_add(float v) {
  int t;
  t = __builtin_amdgcn_update_dpp(0, __builtin_bit_cast(int, v), 0x111, 0xF, 0xF, true);
  v += __builtin_bit_cast(float, t);
  t = __builtin_amdgcn_update_dpp(0, __builtin_bit_cast(int, v), 0x112, 0xF, 0xF, true);
  v += __builtin_bit_cast(float, t);
  t = __builtin_amdgcn_update_dpp(0, __builtin_bit_cast(int, v), 0x114, 0xF, 0xF, true);
  v += __builtin_bit_cast(float, t);
  t = __builtin_amdgcn_update_dpp(0, __builtin_bit_cast(int, v), 0x118, 0xF, 0xF, true);
  v += __builtin_bit_cast(float, t);
  return v;
}

__device__ __forceinline__ float rl(float v, int l) {
  return __builtin_bit_cast(float, __builtin_amdgcn_readlane(__builtin_bit_cast(int, v), l));
}

// ---------------- Fused precompute (blocks 0..255) + KL (blocks 256..319) ----------------
__global__ __launch_bounds__(256, 1) void precompute_kernel(
    const float* __restrict__ state, const float* __restrict__ ac, const float* __restrict__ ms,
    const float* __restrict__ Wst, const float* __restrict__ bst,
    const float* __restrict__ Wac, const float* __restrict__ bac,
    const float* __restrict__ Wem, const float* __restrict__ bem,
    const float* __restrict__ Whd, const float* __restrict__ bhd,
    const float* __restrict__ Wi,  const float* __restrict__ bi,
    const float* __restrict__ lm, const float* __restrict__ lv,
    const float* __restrict__ lmt, const float* __restrict__ lvt,
    const float* __restrict__ dones, const int* __restrict__ actions,
    _Float16* __restrict__ xh, int* __restrict__ aux, float* __restrict__ out) {
  __shared__ float sWst[32 * 64];
  __shared__ float sWem[80 * 64];
  __shared__ float sWhd[24 * 64];
  __shared__ float sWac[8 * 16];
  __shared__ float sb[208];
  __shared__ float sin_[4][48];
  __shared__ float sse[4][80];
  __shared__ float semb[4][64];
  __shared__ float ps[4];
  int tid = threadIdx.x, lane = tid & 63, w = tid >> 6;

  if (blockIdx.x >= 256) {
    // ---- KL: 64 blocks * 256 threads * 16 iters = 262144 items ----
    float total = 0.f;
    for (int it = 0; it < 16; ++it) {
      int idx = ((int)blockIdx.x - 256) * 256 + tid + it * 16384;
      int g = idx & 31;
      int pair = idx >> 5;
      const float* M = (g < 16) ? lm : lmt;
      const float* V = (g < 16) ? lv : lvt;
      int cur = pair * 16 + (g & 15);
      float mu = M[cur], lE = V[cur];
      float m = 0.f, lS = 0.f;
      if (pair >= 64) { m = M[cur - 1024]; lS = V[cur - 1024]; }
      float d = m - mu;
      total += 0.5f * (lS - lE - 1.f + __expf(lE - lS) + d * d * __expf(-lS));
    }
    #pragma unroll
    for (int off = 32; off; off >>= 1) total += __shfl_xor(total, off);
    if (lane == 0) ps[w] = total;
    __syncthreads();
    if (tid == 0) atomicAdd(out, ps[0] + ps[1] + ps[2] + ps[3]);
    return;
  }

  // ---- precompute: 32 (t,b) pairs per block ----
  f32x16 wi0[4], wi1[4], wi2[4];
  #pragma unroll
  for (int k = 0; k < 64; ++k) {
    wi0[k >> 4][k & 15] = Wi[k * 192 + lane];
    wi1[k >> 4][k & 15] = Wi[k * 192 + 64 + lane];
    wi2[k >> 4][k & 15] = Wi[k * 192 + 128 + lane];
  }
  for (int i = tid; i < 32 * 64; i += 256) sWst[i] = Wst[i];
  for (int i = tid; i < 80 * 64; i += 256) sWem[i] = Wem[i];
  for (int i = tid; i < 24 * 64; i += 256) sWhd[i] = Whd[i];
  for (int i = tid; i < 8 * 16; i += 256) sWac[i] = Wac[i];
  if (tid < 64) sb[tid] = bst[tid];
  if (tid < 16) sb[64 + tid] = bac[tid];
  if (tid < 64) sb[80 + tid] = bem[tid];
  if (tid < 64) sb[144 + tid] = bhd[tid];
  float bi0 = bi[lane], bi1 = bi[64 + lane], bi2 = bi[128 + lane];
  __syncthreads();
  for (int cnt = 0; cnt < 8; ++cnt) {
    int pair = blockIdx.x * 32 + w * 8 + cnt;   // t*64 + b, in [0, 8192)
    if (lane < 32)      sin_[w][lane] = state[pair * 32 + lane];
    else if (lane < 40) sin_[w][lane] = ac[pair * 8 + (lane - 32)];
    else if (lane < 48) sin_[w][lane] = ms[pair * 8 + (lane - 40)];
    if (lane == 0) aux[pair] = (dones[pair] > 0.f ? (int)0x80000000 : 0) | actions[pair];
    __syncthreads();
    float se = sb[lane];
    #pragma unroll
    for (int k = 0; k < 32; ++k) se += sin_[w][k] * sWst[k * 64 + lane];
    se = fmaxf(se, 0.f);
    float ae = 0.f;
    if (lane < 16) {
      ae = sb[64 + lane];
      #pragma unroll
      for (int k = 0; k < 8; ++k) ae += sin_[w][32 + k] * sWac[k * 16 + lane];
      ae = fmaxf(ae, 0.f);
    }
    __syncthreads();
    sse[w][lane] = se;
    if (lane < 16) sse[w][64 + lane] = ae;
    __syncthreads();
    float em = sb[80 + lane];
    #pragma unroll
    for (int k = 0; k < 80; ++k) em += sse[w][k] * sWem[k * 64 + lane];
    float hd = sb[144 + lane];
    #pragma unroll
    for (int k = 0; k < 16; ++k) hd += sse[w][64 + k] * sWhd[k * 64 + lane];
    #pragma unroll
    for (int k = 0; k < 8; ++k) hd += sin_[w][40 + k] * sWhd[(16 + k) * 64 + lane];
    semb[w][lane] = em;
    __syncthreads();
    float x0 = bi0, x1 = bi1, x2 = bi2;
    #pragma unroll
    for (int k = 0; k < 64; ++k) {
      float e = semb[w][k];
      x0 += e * wi0[k >> 4][k & 15];
      x1 += e * wi1[k >> 4][k & 15];
      x2 += e * wi2[k >> 4][k & 15];
    }
    _Float16* xo = xh + pair * 256;
    xo[lane] = (_Float16)x0; xo[64 + lane] = (_Float16)x1;
    xo[128 + lane] = (_Float16)x2; xo[192 + lane] = (_Float16)hd;
    __syncthreads();
  }
}

// ---------------- Rollout: phase-locked pair (t=2p, 2p+1) per wave, pk_f16 duals ------
// Two sequences of the same b packed into the two f16 halves of every pk_fma.
// They share xi/aux/hid0 loads and die at the same first done >= tB (A-only death
// at u==tA masked via okA). Emissions accumulate via atomicAdd into shared (s,b)
// slots — the reference sums over t. Phase count = half the step count of R16.
__global__ __launch_bounds__(64, 1) void rollout_kernel(
    const _Float16* __restrict__ xh, const int* __restrict__ aux,
    const float* __restrict__ Whrz, const float* __restrict__ Whn,
    const float* __restrict__ bhn, const float* __restrict__ Wout,
    const float* __restrict__ bout, float* __restrict__ out,
    unsigned int* __restrict__ ctrs) {
  __shared__ __attribute__((aligned(16))) h2 shab[64];   // {hA_k, hB_k}, k = lane
  int lane = threadIdx.x;
  int row = (lane < 18) ? lane : 0;
  h2 Wr[32], Wz[32], Wn[32], Wo[32];   // f16-packed {W_2m, W_2m+1}: 128 regs
  #pragma unroll
  for (int k = 0; k < 32; ++k) {
    Wr[k] = h2{(_Float16)Whrz[(2 * k) * 128 + lane],      (_Float16)Whrz[(2 * k + 1) * 128 + lane]};
    Wz[k] = h2{(_Float16)Whrz[(2 * k) * 128 + 64 + lane], (_Float16)Whrz[(2 * k + 1) * 128 + 64 + lane]};
    Wn[k] = h2{(_Float16)Whn[(2 * k) * 64 + lane],        (_Float16)Whn[(2 * k + 1) * 64 + lane]};
    Wo[k] = h2{(_Float16)Wout[(2 * k) * 18 + row],        (_Float16)Wout[(2 * k + 1) * 18 + row]};
  }
  float bhn_r = bhn[lane];
  float bo_r = bout[row];
  __syncthreads();
  const uint4* shv = (const uint4*)shab;
  int q = blockIdx.x & 7;                        // ~XCD id under round-robin dispatch
  while (true) {
    int i = 0;
    if (lane == 0) i = (int)atomicAdd(&ctrs[q], 1u);
    i = __shfl(i, 0);
    if (i >= 512) break;                         // 512 pairs per queue
    int tp = i >> 3, b = ((i & 7) << 3) | q;     // tp-ascending = longest-first (LPT)
    int tA = tp << 1, tB = tA | 1;
    int u = tA;
    int pr = (u << 6) | b;
    const _Float16* xb = xh + pr * 256;
    float x0 = (float)xb[lane], x1 = (float)xb[64 + lane], x2 = (float)xb[128 + lane];
    float h0u = (float)xb[192 + lane];
    int ax = aux[pr];                            // sign = done, low bits = action
    float hA = h0u, hB = h0u;                    // B is dontcare until u==tB
    bool okA = true;
    shab[lane] = __builtin_bit_cast(h2, __builtin_amdgcn_cvt_pkrtz(hA, hB));
    for (;;) {
      int un = (u < 127) ? u + 1 : 127;
      int prn = (un << 6) | b;
      // -------- prefetch next phase (shared by both seqs; L2-resident slice) --------
      const _Float16* xn = xh + prn * 256;
      float nx0 = (float)xn[lane], nx1 = (float)xn[64 + lane], nx2 = (float)xn[128 + lane];
      float nh0 = (float)xn[192 + lane];
      int nax = aux[prn];
      // -------- gates (h_old), both seqs: 16 uniform b128 reads + 192 pk_fma --------
      h2 ra = {(_Float16)0.f, (_Float16)0.f}, rb = ra, za = ra, zb = ra, na_ = ra, nb_ = ra;
      #pragma unroll
      for (int m = 0; m < 16; ++m) {
        uint4 hv = shv[m];                        // k = 4m..4m+3 as {hA,hB} pairs
        h2 p0 = __builtin_bit_cast(h2, hv.x);
        h2 p1 = __builtin_bit_cast(h2, hv.y);
        h2 p2 = __builtin_bit_cast(h2, hv.z);
        h2 p3 = __builtin_bit_cast(h2, hv.w);
        h2 wr0 = Wr[2 * m], wr1 = Wr[2 * m + 1];
        h2 wz0 = Wz[2 * m], wz1 = Wz[2 * m + 1];
        h2 wn0 = Wn[2 * m], wn1 = Wn[2 * m + 1];
        ra += p0 * sp0(wr0); rb += p1 * sp1(wr0);
        ra += p2 * sp0(wr1); rb += p3 * sp1(wr1);
        za += p0 * sp0(wz0); zb += p1 * sp1(wz0);
        za += p2 * sp0(wz1); zb += p3 * sp1(wz1);
        na_ += p0 * sp0(wn0); nb_ += p1 * sp1(wn0);
        na_ += p2 * sp0(wn1); nb_ += p3 * sp1(wn1);
      }
      float arA = x0 + (float)ra[0] + (float)rb[0];
      float arB = x0 + (float)ra[1] + (float)rb[1];
      float azA = x1 + (float)za[0] + (float)zb[0];
      float azB = x1 + (float)za[1] + (float)zb[1];
      float anA = bhn_r + (float)na_[0] + (float)nb_[0];
      float anB = bhn_r + (float)na_[1] + (float)nb_[1];
      // -------- GRU nonlinearity, both seqs --------
      float rrA = __builtin_amdgcn_rcpf(1.f + __expf(-arA));
      float rrB = __builtin_amdgcn_rcpf(1.f + __expf(-arB));
      float zzA = __builtin_amdgcn_rcpf(1.f + __expf(-azA));
      float zzB = __builtin_amdgcn_rcpf(1.f + __expf(-azB));
      float preA = x2 + rrA * anA;
      float preB = x2 + rrB * anB;
      float nnA = 1.f - 2.f * __builtin_amdgcn_rcpf(1.f + __expf(2.f * preA));
      float nnB = 1.f - 2.f * __builtin_amdgcn_rcpf(1.f + __expf(2.f * preB));
      float hnA = (1.f - zzA) * nnA + zzA * hA;
      float hnB = (1.f - zzB) * nnB + zzB * hB;
      shab[lane] = __builtin_bit_cast(h2, __builtin_amdgcn_cvt_pkrtz(hnA, hnB));
      // -------- logits (h_new), both seqs: 16 reads + 64 pk_fma --------
      h2 la = {(_Float16)0.f, (_Float16)0.f}, lb = la;
      #pragma unroll
      for (int m = 0; m < 16; ++m) {
        uint4 hv = shv[m];
        h2 wo0 = Wo[2 * m], wo1 = Wo[2 * m + 1];
        la += __builtin_bit_cast(h2, hv.x) * sp0(wo0);
        lb += __builtin_bit_cast(h2, hv.y) * sp1(wo0);
        la += __builtin_bit_cast(h2, hv.z) * sp0(wo1);
        lb += __builtin_bit_cast(h2, hv.w) * sp1(wo1);
      }
      float lgA = bo_r + (float)la[0] + (float)lb[0];
      float lgB = bo_r + (float)la[1] + (float)lb[1];
      // -------- softmax via DPP reduce (no max pass; logits small) --------
      float eA = (lane < 18) ? __expf(lgA) : 0.f;
      float eB = (lane < 18) ? __expf(lgB) : 0.f;
      float sA = row16_scan_add(eA);
      float sB = row16_scan_add(eB);
      float ssA = rl(sA, 15) + rl(sA, 31);
      float ssB = rl(sB, 15) + rl(sB, 31);
      int act = ax & 0xFFFF;                     // same action for both seqs (same u)
      float laA = rl(lgA, act);
      float laB = rl(lgB, act);
      if (lane == 0) {
        if (okA)     atomicAdd(&out[1 + (u - tA) * 64 + b], __logf(ssA) - laA);
        if (u >= tB) atomicAdd(&out[1 + (u - tB) * 64 + b], __logf(ssB) - laB);
      }
      // -------- advance / break --------
      bool dpos = ax < 0;
      if ((dpos && u >= tB) || u == 127) break;  // first done >= tB kills both (after emit)
      if (dpos) okA = false;                     // done at u==tA kills A only
      u = un; x0 = nx0; x1 = nx1; x2 = nx2; ax = nax; h0u = nh0;
      bool rstA = (ax < 0);                      // reset BEFORE next cell if done at new u
      bool rstB = rstA || (u == tB);             // B starts fresh at u==tB
      hA = rstA ? h0u : hnA;
      hB = rstB ? h0u : hnB;
      shab[lane] = __builtin_bit_cast(h2, __builtin_amdgcn_cvt_pkrtz(hA, hB));
    }
  }
}

extern "C" void kernel_launch(void* const* d_in, const int* in_sizes, int n_in,
                              void* d_out, int out_size, void* d_ws, size_t ws_size,
                              hipStream_t stream) {
  const float* state = (const float*)d_in[0];
  const float* lm    = (const float*)d_in[1];
  const float* lv    = (const float*)d_in[2];
  const float* lmt   = (const float*)d_in[3];
  const float* lvt   = (const float*)d_in[4];
  const float* ac    = (const float*)d_in[5];
  const float* ms    = (const float*)d_in[6];
  const int*   actions = (const int*)d_in[7];
  const float* dones = (const float*)d_in[8];
  const float* Wst = (const float*)d_in[9],  *bst = (const float*)d_in[10];
  const float* Wac = (const float*)d_in[11], *bac = (const float*)d_in[12];
  const float* Wem = (const float*)d_in[13], *bem = (const float*)d_in[14];
  const float* Whd = (const float*)d_in[15], *bhd = (const float*)d_in[16];
  const float* Wi  = (const float*)d_in[17], *bi  = (const float*)d_in[18];
  const float* Whrz = (const float*)d_in[19];
  const float* Whn  = (const float*)d_in[20], *bhn = (const float*)d_in[21];
  const float* Wout = (const float*)d_in[22], *bout = (const float*)d_in[23];
  float* out = (float*)d_out;
  _Float16* xh = (_Float16*)((char*)d_ws + XH_OFF);
  int* aux = (int*)((char*)d_ws + AUX_OFF);
  unsigned int* ctrs = (unsigned int*)((char*)d_ws + CTR_OFF);

  hipMemsetAsync(d_out, 0, (size_t)out_size * sizeof(float), stream);
  hipMemsetAsync(ctrs, 0, 8 * sizeof(unsigned int), stream);

  hipLaunchKernelGGL(precompute_kernel, dim3(320), dim3(256), 0, stream,
                     state, ac, ms, Wst, bst, Wac, bac, Wem, bem, Whd, bhd, Wi, bi,
                     lm, lv, lmt, lvt, dones, actions, xh, aux, out);
  hipLaunchKernelGGL(rollout_kernel, dim3(2048), dim3(64), 0, stream,
                     xh, aux, Whrz, Whn, bhn, Wout, bout, out, ctrs);
}

// Round 20
// 173.390 us; speedup vs baseline: 1.6700x; 1.6700x over previous
//
#include <hip/hip_runtime.h>

// Problem: T=128, B=64, STATE=32, LATENT=16, AC=8, MS=8, SE=64, AE=16, H=64, OUT=18
// d_out layout: [0] = kl_loss, [1 .. 8192] = recon_loss[s*64+b]  (out_size = 8193, f32)
// d_ws layout:  [0, 4194304)        xh  (T*B, 256) f16: [0:64)=ir,[64:128)=iz,[128:192)=i_n,[192:256)=hid0
//               [4194304, 4227072)  aux (T*B) int: sign bit = done, low bits = action
//               [4227072, +32)      8 work-steal counters (one per XCD queue)

#define XH_OFF   0
#define AUX_OFF  4194304
#define CTR_OFF  4227072

typedef float f32x16 __attribute__((ext_vector_type(16)));
typedef _Float16 h2 __attribute__((ext_vector_type(2)));

#if __has_builtin(__builtin_amdgcn_fdot2)
#define DOT2(a, b, c) __builtin_amdgcn_fdot2((a), (b), (c), false)
#else
#define DOT2(a, b, c) ((c) + (float)(a).x * (float)(b).x + (float)(a).y * (float)(b).y)
#endif

// pack {h[lane], h[lane^1]} into h2 using DPP quad_perm [1,0,3,2] (VALU, no LDS)
__device__ __forceinline__ h2 pack_pair(float h) {
  int hb = __builtin_bit_cast(int, h);
  int hp = __builtin_amdgcn_mov_dpp(hb, 0xB1, 0xF, 0xF, true);  // lane^1
  return __builtin_bit_cast(h2, __builtin_amdgcn_cvt_pkrtz(h, __builtin_bit_cast(float, hp)));
}

// after this, lane15 holds sum(lanes 0..15), lane31 holds sum(lanes 16..31) (row_shr scan)
__device__ __forceinline__ float row16_scan_add(float v) {
  int t;
  t = __builtin_amdgcn_update_dpp(0, __builtin_bit_cast(int, v), 0x111, 0xF, 0xF, true);
  v += __builtin_bit_cast(float, t);
  t = __builtin_amdgcn_update_dpp(0, __builtin_bit_cast(int, v), 0x112, 0xF, 0xF, true);
  v += __builtin_bit_cast(float, t);
  t = __builtin_amdgcn_update_dpp(0, __builtin_bit_cast(int, v), 0x114, 0xF, 0xF, true);
  v += __builtin_bit_cast(float, t);
  t = __builtin_amdgcn_update_dpp(0, __builtin_bit_cast(int, v), 0x118, 0xF, 0xF, true);
  v += __builtin_bit_cast(float, t);
  return v;
}

__device__ __forceinline__ float rl(float v, int l) {
  return __builtin_bit_cast(float, __builtin_amdgcn_readlane(__builtin_bit_cast(int, v), l));
}

// ---------------- Fused precompute (blocks 0..255) + KL (blocks 256..319) ----------------
__global__ __launch_bounds__(256, 1) void precompute_kernel(
    const float* __restrict__ state, const float* __restrict__ ac, const float* __restrict__ ms,
    const float* __restrict__ Wst, const float* __restrict__ bst,
    const float* __restrict__ Wac, const float* __restrict__ bac,
    const float* __restrict__ Wem, const float* __restrict__ bem,
    const float* __restrict__ Whd, const float* __restrict__ bhd,
    const float* __restrict__ Wi,  const float* __restrict__ bi,
    const float* __restrict__ lm, const float* __restrict__ lv,
    const float* __restrict__ lmt, const float* __restrict__ lvt,
    const float* __restrict__ dones, const int* __restrict__ actions,
    _Float16* __restrict__ xh, int* __restrict__ aux, float* __restrict__ out) {
  __shared__ float sWst[32 * 64];
  __shared__ float sWem[80 * 64];
  __shared__ float sWhd[24 * 64];
  __shared__ float sWac[8 * 16];
  __shared__ float sb[208];
  __shared__ float sin_[4][48];
  __shared__ float sse[4][80];
  __shared__ float semb[4][64];
  __shared__ float ps[4];
  int tid = threadIdx.x, lane = tid & 63, w = tid >> 6;

  if (blockIdx.x >= 256) {
    // ---- KL: 64 blocks * 256 threads * 16 iters = 262144 items ----
    float total = 0.f;
    for (int it = 0; it < 16; ++it) {
      int idx = ((int)blockIdx.x - 256) * 256 + tid + it * 16384;
      int g = idx & 31;
      int pair = idx >> 5;
      const float* M = (g < 16) ? lm : lmt;
      const float* V = (g < 16) ? lv : lvt;
      int cur = pair * 16 + (g & 15);
      float mu = M[cur], lE = V[cur];
      float m = 0.f, lS = 0.f;
      if (pair >= 64) { m = M[cur - 1024]; lS = V[cur - 1024]; }
      float d = m - mu;
      total += 0.5f * (lS - lE - 1.f + __expf(lE - lS) + d * d * __expf(-lS));
    }
    #pragma unroll
    for (int off = 32; off; off >>= 1) total += __shfl_xor(total, off);
    if (lane == 0) ps[w] = total;
    __syncthreads();
    if (tid == 0) atomicAdd(out, ps[0] + ps[1] + ps[2] + ps[3]);
    return;
  }

  // ---- precompute: 32 (t,b) pairs per block ----
  f32x16 wi0[4], wi1[4], wi2[4];
  #pragma unroll
  for (int k = 0; k < 64; ++k) {
    wi0[k >> 4][k & 15] = Wi[k * 192 + lane];
    wi1[k >> 4][k & 15] = Wi[k * 192 + 64 + lane];
    wi2[k >> 4][k & 15] = Wi[k * 192 + 128 + lane];
  }
  for (int i = tid; i < 32 * 64; i += 256) sWst[i] = Wst[i];
  for (int i = tid; i < 80 * 64; i += 256) sWem[i] = Wem[i];
  for (int i = tid; i < 24 * 64; i += 256) sWhd[i] = Whd[i];
  for (int i = tid; i < 8 * 16; i += 256) sWac[i] = Wac[i];
  if (tid < 64) sb[tid] = bst[tid];
  if (tid < 16) sb[64 + tid] = bac[tid];
  if (tid < 64) sb[80 + tid] = bem[tid];
  if (tid < 64) sb[144 + tid] = bhd[tid];
  float bi0 = bi[lane], bi1 = bi[64 + lane], bi2 = bi[128 + lane];
  __syncthreads();
  for (int cnt = 0; cnt < 8; ++cnt) {
    int pair = blockIdx.x * 32 + w * 8 + cnt;   // t*64 + b, in [0, 8192)
    if (lane < 32)      sin_[w][lane] = state[pair * 32 + lane];
    else if (lane < 40) sin_[w][lane] = ac[pair * 8 + (lane - 32)];
    else if (lane < 48) sin_[w][lane] = ms[pair * 8 + (lane - 40)];
    if (lane == 0) aux[pair] = (dones[pair] > 0.f ? (int)0x80000000 : 0) | actions[pair];
    __syncthreads();
    float se = sb[lane];
    #pragma unroll
    for (int k = 0; k < 32; ++k) se += sin_[w][k] * sWst[k * 64 + lane];
    se = fmaxf(se, 0.f);
    float ae = 0.f;
    if (lane < 16) {
      ae = sb[64 + lane];
      #pragma unroll
      for (int k = 0; k < 8; ++k) ae += sin_[w][32 + k] * sWac[k * 16 + lane];
      ae = fmaxf(ae, 0.f);
    }
    __syncthreads();
    sse[w][lane] = se;
    if (lane < 16) sse[w][64 + lane] = ae;
    __syncthreads();
    float em = sb[80 + lane];
    #pragma unroll
    for (int k = 0; k < 80; ++k) em += sse[w][k] * sWem[k * 64 + lane];
    float hd = sb[144 + lane];
    #pragma unroll
    for (int k = 0; k < 16; ++k) hd += sse[w][64 + k] * sWhd[k * 64 + lane];
    #pragma unroll
    for (int k = 0; k < 8; ++k) hd += sin_[w][40 + k] * sWhd[(16 + k) * 64 + lane];
    semb[w][lane] = em;
    __syncthreads();
    float x0 = bi0, x1 = bi1, x2 = bi2;
    #pragma unroll
    for (int k = 0; k < 64; ++k) {
      float e = semb[w][k];
      x0 += e * wi0[k >> 4][k & 15];
      x1 += e * wi1[k >> 4][k & 15];
      x2 += e * wi2[k >> 4][k & 15];
    }
    _Float16* xo = xh + pair * 256;
    xo[lane] = (_Float16)x0; xo[64 + lane] = (_Float16)x1;
    xo[128 + lane] = (_Float16)x2; xo[192 + lane] = (_Float16)hd;
    __syncthreads();
  }
}

// ---------------- Rollout: one wave per (t,b) sequence, XCD-local queues ----------------
// R18 body (153.7us, VGPR 112) + LDS emission buffer: the per-step device-scope
// atomicAdd shares the vmcnt counter with the prefetch loads, so conservative
// s_waitcnt vmcnt() made every step wait on the previous step's atomic round-trip.
// Now: 1 ds_write per step (never read until seq end), flush with 2 lane-parallel
// vector atomics per sequence (143K global atomics -> 16K, all off critical path).
__global__ __launch_bounds__(64, 2) void rollout_kernel(
    const _Float16* __restrict__ xh, const int* __restrict__ aux,
    const float* __restrict__ Whrz, const float* __restrict__ Whn,
    const float* __restrict__ bhn, const float* __restrict__ Wout,
    const float* __restrict__ bout, float* __restrict__ out,
    unsigned int* __restrict__ ctrs) {
  __shared__ __attribute__((aligned(16))) h2 sh2[32];        // packed h broadcast
  __shared__ __attribute__((aligned(16))) float emit[128];   // per-step emissions
  int lane = threadIdx.x;
  int row = (lane < 18) ? lane : 0;
  h2 Wr[32], Wz[32], Wn[32], Wo[32];   // f16-packed: 128 regs
  #pragma unroll
  for (int k = 0; k < 32; ++k) {
    Wr[k] = h2{(_Float16)Whrz[(2 * k) * 128 + lane],      (_Float16)Whrz[(2 * k + 1) * 128 + lane]};
    Wz[k] = h2{(_Float16)Whrz[(2 * k) * 128 + 64 + lane], (_Float16)Whrz[(2 * k + 1) * 128 + 64 + lane]};
    Wn[k] = h2{(_Float16)Whn[(2 * k) * 64 + lane],        (_Float16)Whn[(2 * k + 1) * 64 + lane]};
    Wo[k] = h2{(_Float16)Wout[(2 * k) * 18 + row],        (_Float16)Wout[(2 * k + 1) * 18 + row]};
  }
  float bhn_r = bhn[lane];
  float bo_r = bout[row];
  __syncthreads();
  const uint4* shv = (const uint4*)sh2;
  int q = blockIdx.x & 7;                        // ~XCD id under round-robin dispatch
  while (true) {
    int i = 0;
    if (lane == 0) i = (int)atomicAdd(&ctrs[q], 1u);
    i = __shfl(i, 0);
    if (i >= 1024) break;
    int t = i >> 3, b = ((i & 7) << 3) | q;      // queue q owns b&7==q; t-ascending (LPT)
    int u = t;
    int pr = (t << 6) | b;
    const _Float16* xb = xh + pr * 256;
    float h = (float)xb[192 + lane];             // covers the s=0 reset case too
    float x0 = (float)xb[lane], x1 = (float)xb[64 + lane], x2 = (float)xb[128 + lane];
    int ax = aux[pr];                            // sign = done, low bits = action
    if ((lane & 1) == 0) sh2[lane >> 1] = pack_pair(h);
    int len = 0;
    for (int s = 0;; ++s) {
      int un = (u < 127) ? u + 1 : 127;
      int prn = (un << 6) | b;
      // -------- prefetch next step (one 512B row + aux; L2-resident slice) --------
      const _Float16* xn = xh + prn * 256;
      float nx0 = (float)xn[lane], nx1 = (float)xn[64 + lane], nx2 = (float)xn[128 + lane];
      float nh = (float)xn[192 + lane];
      int nax = aux[prn];
      // -------- GRU gates: 8 uniform b128 reads + 96 dot2 --------
      float ara = x0, arb = 0.f, aza = x1, azb = 0.f, ana = 0.f, anb = 0.f;
      #pragma unroll
      for (int qq = 0; qq < 8; ++qq) {
        uint4 hv = shv[qq];                       // broadcast (same addr all lanes)
        h2 a0 = __builtin_bit_cast(h2, hv.x);
        h2 a1 = __builtin_bit_cast(h2, hv.y);
        h2 a2 = __builtin_bit_cast(h2, hv.z);
        h2 a3 = __builtin_bit_cast(h2, hv.w);
        ara = DOT2(a0, Wr[4 * qq + 0], ara); arb = DOT2(a1, Wr[4 * qq + 1], arb);
        ara = DOT2(a2, Wr[4 * qq + 2], ara); arb = DOT2(a3, Wr[4 * qq + 3], arb);
        aza = DOT2(a0, Wz[4 * qq + 0], aza); azb = DOT2(a1, Wz[4 * qq + 1], azb);
        aza = DOT2(a2, Wz[4 * qq + 2], aza); azb = DOT2(a3, Wz[4 * qq + 3], azb);
        ana = DOT2(a0, Wn[4 * qq + 0], ana); anb = DOT2(a1, Wn[4 * qq + 1], anb);
        ana = DOT2(a2, Wn[4 * qq + 2], ana); anb = DOT2(a3, Wn[4 * qq + 3], anb);
      }
      float ar = ara + arb, az = aza + azb, an = ana + anb;
      float r = __builtin_amdgcn_rcpf(1.f + __expf(-ar));
      float z = __builtin_amdgcn_rcpf(1.f + __expf(-az));
      float pre = x2 + r * (an + bhn_r);
      float n = 1.f - 2.f * __builtin_amdgcn_rcpf(1.f + __expf(2.f * pre));  // tanh
      float hn = (1.f - z) * n + z * h;
      // -------- broadcast h_new; logits via register W_out rows --------
      if ((lane & 1) == 0) sh2[lane >> 1] = pack_pair(hn);
      float la_a = bo_r, la_b = 0.f;
      #pragma unroll
      for (int qq = 0; qq < 8; ++qq) {
        uint4 hv = shv[qq];
        la_a = DOT2(__builtin_bit_cast(h2, hv.x), Wo[4 * qq + 0], la_a);
        la_b = DOT2(__builtin_bit_cast(h2, hv.y), Wo[4 * qq + 1], la_b);
        la_a = DOT2(__builtin_bit_cast(h2, hv.z), Wo[4 * qq + 2], la_a);
        la_b = DOT2(__builtin_bit_cast(h2, hv.w), Wo[4 * qq + 3], la_b);
      }
      float logit = la_a + la_b;
      // -------- softmax via DPP reduce (no LDS roundtrip; logits small: no max pass) ----
      float e = (lane < 18) ? __expf(logit) : 0.f;
      float er = row16_scan_add(e);              // lane15 = sum(0..15), lane31 = sum(16..31)
      float ssum = rl(er, 15) + rl(er, 31);
      int act = ax & 0xFFFF;
      float la = rl(logit, act);
      // buffer emission in LDS (write-only until seq end — off the critical path)
      if (lane == 0) emit[s] = __logf(ssum) - la;
      if (ax < 0 || u == 127) { len = s + 1; break; }  // done: mask 0 for later steps
      // -------- advance --------
      u = un; x0 = nx0; x1 = nx1; x2 = nx2; ax = nax;
      if (nax < 0) {
        h = nh;                                  // episode reset at next step start
        if ((lane & 1) == 0) sh2[lane >> 1] = pack_pair(h);
      } else {
        h = hn;                                  // sh2 already holds hn
      }
    }
    // -------- flush: lane j -> out[1 + j*64 + b], two rounds cover s < 128 ----------
    if (lane < len)      atomicAdd(&out[1 + lane * 64 + b], emit[lane]);
    if (64 + lane < len) atomicAdd(&out[1 + (64 + lane) * 64 + b], emit[64 + lane]);
  }
}

extern "C" void kernel_launch(void* const* d_in, const int* in_sizes, int n_in,
                              void* d_out, int out_size, void* d_ws, size_t ws_size,
                              hipStream_t stream) {
  const float* state = (const float*)d_in[0];
  const float* lm    = (const float*)d_in[1];
  const float* lv    = (const float*)d_in[2];
  const float* lmt   = (const float*)d_in[3];
  const float* lvt   = (const float*)d_in[4];
  const float* ac    = (const float*)d_in[5];
  const float* ms    = (const float*)d_in[6];
  const int*   actions = (const int*)d_in[7];
  const float* dones = (const float*)d_in[8];
  const float* Wst = (const float*)d_in[9],  *bst = (const float*)d_in[10];
  const float* Wac = (const float*)d_in[11], *bac = (const float*)d_in[12];
  const float* Wem = (const float*)d_in[13], *bem = (const float*)d_in[14];
  const float* Whd = (const float*)d_in[15], *bhd = (const float*)d_in[16];
  const float* Wi  = (const float*)d_in[17], *bi  = (const float*)d_in[18];
  const float* Whrz = (const float*)d_in[19];
  const float* Whn  = (const float*)d_in[20], *bhn = (const float*)d_in[21];
  const float* Wout = (const float*)d_in[22], *bout = (const float*)d_in[23];
  float* out = (float*)d_out;
  _Float16* xh = (_Float16*)((char*)d_ws + XH_OFF);
  int* aux = (int*)((char*)d_ws + AUX_OFF);
  unsigned int* ctrs = (unsigned int*)((char*)d_ws + CTR_OFF);

  hipMemsetAsync(d_out, 0, (size_t)out_size * sizeof(float), stream);
  hipMemsetAsync(ctrs, 0, 8 * sizeof(unsigned int), stream);

  hipLaunchKernelGGL(precompute_kernel, dim3(320), dim3(256), 0, stream,
                     state, ac, ms, Wst, bst, Wac, bac, Wem, bem, Whd, bhd, Wi, bi,
                     lm, lv, lmt, lvt, dones, actions, xh, aux, out);
  hipLaunchKernelGGL(rollout_kernel, dim3(2048), dim3(64), 0, stream,
                     xh, aux, Whrz, Whn, bhn, Wout, bout, out, ctrs);
}